// Round 1
// baseline (852.776 us; speedup 1.0000x reference)
//
#include <hip/hip_runtime.h>
#include <math.h>

// Problem constants (MultiHeadAttentionMemory_84748294685256)
//   x: [256,256,4,4] -> z: [B=256, F=4096]
//   memory: [4096, 4096]
//   seq_len == 1  =>  softmax(scores)=1  =>  MHA output = (z@Wv+bv)@Wo+bo
//   (Wq/bq/Wk/bk are dead code)
#define MBATCH 256
#define FEAT   4096
#define NMEM   4096

__device__ __forceinline__ float block_reduce_sum(float v, float* red) {
    const int tid = threadIdx.x;
    red[tid] = v;
    __syncthreads();
    for (int s = 128; s > 0; s >>= 1) {
        if (tid < s) red[tid] += red[tid + s];
        __syncthreads();
    }
    float r = red[0];
    __syncthreads();
    return r;
}

__device__ __forceinline__ float block_reduce_max(float v, float* red) {
    const int tid = threadIdx.x;
    red[tid] = v;
    __syncthreads();
    for (int s = 128; s > 0; s >>= 1) {
        if (tid < s) red[tid] = fmaxf(red[tid], red[tid + s]);
        __syncthreads();
    }
    float r = red[0];
    __syncthreads();
    return r;
}

// dst[row] = max(||src[row,:]||_2, 1e-8)
__global__ __launch_bounds__(256) void rownorm_kernel(
    const float* __restrict__ src, float* __restrict__ dst, int ncols)
{
    __shared__ float red[256];
    const int row = blockIdx.x;
    const int tid = threadIdx.x;
    const float4* p = (const float4*)(src + (size_t)row * ncols);
    float s = 0.f;
    for (int i = tid; i < ncols / 4; i += 256) {
        float4 v = p[i];
        s += v.x * v.x + v.y * v.y + v.z * v.z + v.w * v.w;
    }
    float tot = block_reduce_sum(s, red);
    if (tid == 0) dst[row] = fmaxf(sqrtf(tot), 1e-8f);
}

// C[M,N] = A[M,K] @ B (+epilogue).
// BLAYOUT 0: B is [K,N] row-major.  BLAYOUT 1: B is [N,K] row-major (B^T input).
// EPI 0: += bias[col].  EPI 1: /= (zn[row]*mn[col]).  EPI 2: plain.
// Assumes M%64==0, N%64==0, K%32==0.
template <int BLAYOUT, int EPI>
__global__ __launch_bounds__(256) void gemm64(
    const float* __restrict__ A, const float* __restrict__ B,
    const float* __restrict__ bias, const float* __restrict__ zn,
    const float* __restrict__ mn, float* __restrict__ C,
    int M, int N, int K)
{
    constexpr int BM = 64, BN = 64, BK = 32;
    __shared__ __align__(16) float As[BM * (BK + 1)];
    __shared__ __align__(16) float Bs[BLAYOUT ? BN * (BK + 1) : BK * BN];

    const int tid = threadIdx.x;
    const int m0 = blockIdx.y * BM;
    const int n0 = blockIdx.x * BN;
    const int tr = tid >> 4;    // 0..15
    const int tc = tid & 15;    // 0..15

    float acc[4][4] = {};

    for (int kk = 0; kk < K; kk += BK) {
        // ---- load A tile: 64 rows x 32 k = 512 float4, 2 per thread
#pragma unroll
        for (int l = 0; l < 2; ++l) {
            int idx = tid + l * 256;
            int mm = idx >> 3;
            int kq = (idx & 7) << 2;
            float4 v = *(const float4*)(A + (size_t)(m0 + mm) * K + kk + kq);
            float* d = &As[mm * (BK + 1) + kq];
            d[0] = v.x; d[1] = v.y; d[2] = v.z; d[3] = v.w;
        }
        // ---- load B tile
        if constexpr (BLAYOUT == 0) {
            // B[K,N]: rows kk..kk+31, cols n0..n0+63 -> Bs[k][n], layout matches load order
#pragma unroll
            for (int l = 0; l < 2; ++l) {
                int idx = tid + l * 256;
                int kr = idx >> 4;
                int nq = (idx & 15) << 2;
                float4 v = *(const float4*)(B + (size_t)(kk + kr) * N + n0 + nq);
                *(float4*)(&Bs[kr * BN + nq]) = v;
            }
        } else {
            // B[N,K]: rows n0..n0+63, k cols kk..kk+31 -> Bs[n][k] padded
#pragma unroll
            for (int l = 0; l < 2; ++l) {
                int idx = tid + l * 256;
                int nn = idx >> 3;
                int kq = (idx & 7) << 2;
                float4 v = *(const float4*)(B + (size_t)(n0 + nn) * K + kk + kq);
                float* d = &Bs[nn * (BK + 1) + kq];
                d[0] = v.x; d[1] = v.y; d[2] = v.z; d[3] = v.w;
            }
        }
        __syncthreads();

#pragma unroll
        for (int k = 0; k < BK; ++k) {
            float a0 = As[(tr * 4 + 0) * (BK + 1) + k];
            float a1 = As[(tr * 4 + 1) * (BK + 1) + k];
            float a2 = As[(tr * 4 + 2) * (BK + 1) + k];
            float a3 = As[(tr * 4 + 3) * (BK + 1) + k];
            float b0, b1, b2, b3;
            if constexpr (BLAYOUT == 0) {
                float4 bv = *(const float4*)(&Bs[k * BN + tc * 4]);
                b0 = bv.x; b1 = bv.y; b2 = bv.z; b3 = bv.w;
            } else {
                b0 = Bs[(tc * 4 + 0) * (BK + 1) + k];
                b1 = Bs[(tc * 4 + 1) * (BK + 1) + k];
                b2 = Bs[(tc * 4 + 2) * (BK + 1) + k];
                b3 = Bs[(tc * 4 + 3) * (BK + 1) + k];
            }
            acc[0][0] += a0 * b0; acc[0][1] += a0 * b1; acc[0][2] += a0 * b2; acc[0][3] += a0 * b3;
            acc[1][0] += a1 * b0; acc[1][1] += a1 * b1; acc[1][2] += a1 * b2; acc[1][3] += a1 * b3;
            acc[2][0] += a2 * b0; acc[2][1] += a2 * b1; acc[2][2] += a2 * b2; acc[2][3] += a2 * b3;
            acc[3][0] += a3 * b0; acc[3][1] += a3 * b1; acc[3][2] += a3 * b2; acc[3][3] += a3 * b3;
        }
        __syncthreads();
    }

#pragma unroll
    for (int i = 0; i < 4; ++i) {
        const int row = m0 + tr * 4 + i;
#pragma unroll
        for (int j = 0; j < 4; ++j) {
            const int col = n0 + tc * 4 + j;
            float c = acc[i][j];
            if constexpr (EPI == 0) c += bias[col];
            if constexpr (EPI == 1) c = c / (zn[row] * mn[col]);
            C[(size_t)row * N + col] = c;
        }
    }
}

// Per-row (256 rows, 4096 cols): softmax -> sparse shrinkage -> L1 renorm -> entropy.
// In-place safe (row staged in LDS before any write).
__global__ __launch_bounds__(256) void softmax_shrink_kernel(
    const float* __restrict__ logits, float* __restrict__ wout,
    float* __restrict__ rowent, int N)
{
    constexpr float THRESH = 1.0f / 4096.0f;
    constexpr float EPS = 1e-12f;
    __shared__ float srow[4096];
    __shared__ float red[256];
    const int row = blockIdx.x;
    const int tid = threadIdx.x;

    const float4* p = (const float4*)(logits + (size_t)row * N);
    for (int i = tid; i < N / 4; i += 256) ((float4*)srow)[i] = p[i];
    __syncthreads();

    float m = -INFINITY;
    for (int i = tid; i < N; i += 256) m = fmaxf(m, srow[i]);
    m = block_reduce_max(m, red);

    float s = 0.f;
    for (int i = tid; i < N; i += 256) {
        float e = expf(srow[i] - m);
        srow[i] = e;
        s += e;
    }
    s = block_reduce_sum(s, red);
    const float inv = 1.0f / s;

    float s2 = 0.f;
    for (int i = tid; i < N; i += 256) {
        float w = srow[i] * inv;
        float d = w - THRESH;
        float w2 = fmaxf(d, 0.f) * w / (fabsf(d) + EPS);
        srow[i] = w2;
        s2 += w2;  // w2 >= 0, so sum(|w2|) == sum(w2)
    }
    __syncthreads();
    s2 = block_reduce_sum(s2, red);
    const float inv2 = 1.0f / fmaxf(s2, EPS);

    float ent = 0.f;
    for (int i = tid; i < N; i += 256) {
        float w3 = srow[i] * inv2;
        wout[(size_t)row * N + i] = w3;
        ent -= w3 * logf(w3 + EPS);
    }
    ent = block_reduce_sum(ent, red);
    if (tid == 0) rowent[row] = ent;
}

// mem_loss = (sum_b rowent[b] / B) * ENTROPY_COEF
__global__ __launch_bounds__(256) void loss_kernel(
    const float* __restrict__ rowent, float* __restrict__ out)
{
    __shared__ float red[256];
    const int tid = threadIdx.x;
    float tot = block_reduce_sum(rowent[tid], red);
    if (tid == 0) out[0] = (tot / 256.0f) * 0.0002f;
}

extern "C" void kernel_launch(void* const* d_in, const int* in_sizes, int n_in,
                              void* d_out, int out_size, void* d_ws, size_t ws_size,
                              hipStream_t stream)
{
    // setup_inputs order: x, memory, Wq, bq, Wk, bk, Wv, bv, Wo, bo
    const float* x   = (const float*)d_in[0];
    const float* mem = (const float*)d_in[1];
    const float* Wv  = (const float*)d_in[6];
    const float* bv  = (const float*)d_in[7];
    const float* Wo  = (const float*)d_in[8];
    const float* bo  = (const float*)d_in[9];
    float* out = (float*)d_out;

    // workspace layout (floats): v[1M] | o[1M] | w[1M] | mn[4096] | zn[256] | rowent[256]
    float* v      = (float*)d_ws;
    float* o      = v + (1 << 20);
    float* wbuf   = o + (1 << 20);
    float* mn     = wbuf + (1 << 20);
    float* zn     = mn + NMEM;
    float* rowent = zn + MBATCH;

    const int M = MBATCH, F = FEAT, NM = NMEM;
    dim3 blk(256);
    dim3 grd(F / 64, M / 64);

    // memory row norms (clamped)
    rownorm_kernel<<<NM, blk, 0, stream>>>(mem, mn, F);
    // v = z @ Wv + bv   (seq_len==1 => attention is identity on v)
    gemm64<0, 0><<<grd, blk, 0, stream>>>(x, Wv, bv, nullptr, nullptr, v, M, F, F);
    // o = v @ Wo + bo
    gemm64<0, 0><<<grd, blk, 0, stream>>>(v, Wo, bo, nullptr, nullptr, o, M, F, F);
    // zn = row norms of o (clamped)
    rownorm_kernel<<<M, blk, 0, stream>>>(o, zn, F);
    // logits = (o @ mem^T) / (zn x mn)
    gemm64<1, 1><<<dim3(NM / 64, M / 64), blk, 0, stream>>>(o, mem, nullptr, zn, mn, wbuf, M, NM, F);
    // softmax + shrinkage + renorm + entropy (in place)
    softmax_shrink_kernel<<<M, blk, 0, stream>>>(wbuf, wbuf, rowent, NM);
    // z_hat = w @ mem  -> d_out[0 .. 1M)
    gemm64<0, 2><<<grd, blk, 0, stream>>>(wbuf, mem, nullptr, nullptr, nullptr, out, M, F, NM);
    // mem_loss -> d_out[1M]
    loss_kernel<<<1, blk, 0, stream>>>(rowent, out + (size_t)M * F);
}

// Round 2
// 485.207 us; speedup vs baseline: 1.7576x; 1.7576x over previous
//
#include <hip/hip_runtime.h>
#include <math.h>

// MultiHeadAttentionMemory: B=256, F=4096, M=4096 memories.
// seq_len==1 => attention==identity => o = (z@Wv+bv)@Wo+bo  (Wq/Wk dead).
// Pipeline: split-bf16 MFMA GEMMs (4-product hi/lo) for the 3 precision-
// sensitive GEMMs, plain bf16 MFMA for z_hat = w@mem.
#define MB 256
#define FF 4096

typedef __attribute__((ext_vector_type(8))) short short8v;
typedef __attribute__((ext_vector_type(4))) short short4v;
typedef __attribute__((ext_vector_type(16))) float f32x16;

__device__ __forceinline__ unsigned short bf16_rne(float f) {
    unsigned u = __builtin_bit_cast(unsigned, f);
    u += 0x7fffu + ((u >> 16) & 1u);
    return (unsigned short)(u >> 16);
}
__device__ __forceinline__ float bf16_f(unsigned short h) {
    unsigned u = ((unsigned)h) << 16;
    return __builtin_bit_cast(float, u);
}

// ---------------- reductions ----------------
__device__ __forceinline__ float block_reduce_sum(float v, float* red) {
    const int tid = threadIdx.x;
    red[tid] = v; __syncthreads();
    for (int s = 128; s > 0; s >>= 1) {
        if (tid < s) red[tid] += red[tid + s];
        __syncthreads();
    }
    float r = red[0]; __syncthreads();
    return r;
}
__device__ __forceinline__ float block_reduce_max(float v, float* red) {
    const int tid = threadIdx.x;
    red[tid] = v; __syncthreads();
    for (int s = 128; s > 0; s >>= 1) {
        if (tid < s) red[tid] = fmaxf(red[tid], red[tid + s]);
        __syncthreads();
    }
    float r = red[0]; __syncthreads();
    return r;
}

// dst[row] = max(||src[row,:]||, 1e-8)
__global__ __launch_bounds__(256) void rownorm_kernel(
    const float* __restrict__ src, float* __restrict__ dst, int ncols)
{
    __shared__ float red[256];
    const int row = blockIdx.x, tid = threadIdx.x;
    const float4* p = (const float4*)(src + (size_t)row * ncols);
    float s = 0.f;
    for (int i = tid; i < ncols / 4; i += 256) {
        float4 v = p[i];
        s += v.x * v.x + v.y * v.y + v.z * v.z + v.w * v.w;
    }
    float tot = block_reduce_sum(s, red);
    if (tid == 0) dst[row] = fmaxf(sqrtf(tot), 1e-8f);
}

// ---------------- fp32 -> bf16 hi/lo split (straight) ----------------
__global__ __launch_bounds__(256) void split_plain(
    const float* __restrict__ src, unsigned short* __restrict__ hi,
    unsigned short* __restrict__ lo)
{
    const size_t i4 = (size_t)blockIdx.x * 256 + threadIdx.x;
    const float4 v = *(const float4*)(src + i4 * 4);
    unsigned short h0 = bf16_rne(v.x), h1 = bf16_rne(v.y), h2 = bf16_rne(v.z), h3 = bf16_rne(v.w);
    short4v hv = { (short)h0, (short)h1, (short)h2, (short)h3 };
    *(short4v*)(hi + i4 * 4) = hv;
    short4v lv = { (short)bf16_rne(v.x - bf16_f(h0)), (short)bf16_rne(v.y - bf16_f(h1)),
                   (short)bf16_rne(v.z - bf16_f(h2)), (short)bf16_rne(v.w - bf16_f(h3)) };
    *(short4v*)(lo + i4 * 4) = lv;
}

// ---------------- transpose + split: src[4096][4096] f32 -> dstT[n][k] bf16 ----------------
template <int WRITE_LO>
__global__ __launch_bounds__(256) void transpose_split(
    const float* __restrict__ src, unsigned short* __restrict__ hi,
    unsigned short* __restrict__ lo)
{
    __shared__ float tile[32][33];
    const int bj = blockIdx.x;  // col block of src (= out row block)
    const int bi = blockIdx.y;  // row block of src (= out col block)
    const int t = threadIdx.x;
    const int ty = t >> 3, tx4 = (t & 7) << 2;
    const float4 v = *(const float4*)(src + (size_t)(bi * 32 + ty) * FF + bj * 32 + tx4);
    tile[ty][tx4 + 0] = v.x; tile[ty][tx4 + 1] = v.y;
    tile[ty][tx4 + 2] = v.z; tile[ty][tx4 + 3] = v.w;
    __syncthreads();
    float o0 = tile[tx4 + 0][ty], o1 = tile[tx4 + 1][ty];
    float o2 = tile[tx4 + 2][ty], o3 = tile[tx4 + 3][ty];
    unsigned short h0 = bf16_rne(o0), h1 = bf16_rne(o1), h2 = bf16_rne(o2), h3 = bf16_rne(o3);
    const size_t ob = (size_t)(bj * 32 + ty) * FF + bi * 32 + tx4;
    short4v hv = { (short)h0, (short)h1, (short)h2, (short)h3 };
    *(short4v*)(hi + ob) = hv;
    if constexpr (WRITE_LO) {
        short4v lv = { (short)bf16_rne(o0 - bf16_f(h0)), (short)bf16_rne(o1 - bf16_f(h1)),
                       (short)bf16_rne(o2 - bf16_f(h2)), (short)bf16_rne(o3 - bf16_f(h3)) };
        *(short4v*)(lo + ob) = lv;
    }
}

// ---------------- MFMA GEMM, split-K ----------------
// C[256][4096] = A[256][4096] @ BT[4096][4096]^T   (BT stored [n][k])
// grid (32, 4, 8); block 256 = 4 waves (2x2 of 32x64 tiles); K-chunk 512.
// SPLIT=1: full (Ah+Al)(Bh+Bl) -> 4 MFMAs per frag pair.
template <int SPLIT>
__global__ __launch_bounds__(256) void gemm_sk(
    const unsigned short* __restrict__ Ah, const unsigned short* __restrict__ Al,
    const unsigned short* __restrict__ Bh, const unsigned short* __restrict__ Bl,
    float* __restrict__ part)
{
    const int tid = threadIdx.x;
    const int lane = tid & 63, w = tid >> 6;
    const int wr = w >> 1, wc = w & 1;
    const int m0 = blockIdx.y * 64 + wr * 32;
    const int n0 = blockIdx.x * 128 + wc * 64;
    const int k0 = blockIdx.z * 512;
    const int l31 = lane & 31;
    const int lk = (lane >> 5) * 8;

    f32x16 acc0 = 0.0f, acc1 = 0.0f;

    const unsigned short* aph = Ah + (size_t)(m0 + l31) * FF + k0 + lk;
    const unsigned short* bph0 = Bh + (size_t)(n0 + l31) * FF + k0 + lk;
    const unsigned short* bph1 = bph0 + (size_t)32 * FF;
    const unsigned short* apl = SPLIT ? (Al + (size_t)(m0 + l31) * FF + k0 + lk) : aph;
    const unsigned short* bpl0 = SPLIT ? (Bl + (size_t)(n0 + l31) * FF + k0 + lk) : bph0;
    const unsigned short* bpl1 = bpl0 + (size_t)32 * FF;

#pragma unroll 2
    for (int ks = 0; ks < 32; ++ks) {
        short8v ah = *(const short8v*)aph;
        short8v bh0 = *(const short8v*)bph0;
        short8v bh1 = *(const short8v*)bph1;
        acc0 = __builtin_amdgcn_mfma_f32_32x32x16_bf16(ah, bh0, acc0, 0, 0, 0);
        acc1 = __builtin_amdgcn_mfma_f32_32x32x16_bf16(ah, bh1, acc1, 0, 0, 0);
        if constexpr (SPLIT) {
            short8v al = *(const short8v*)apl;
            short8v bl0 = *(const short8v*)bpl0;
            short8v bl1 = *(const short8v*)bpl1;
            acc0 = __builtin_amdgcn_mfma_f32_32x32x16_bf16(ah, bl0, acc0, 0, 0, 0);
            acc1 = __builtin_amdgcn_mfma_f32_32x32x16_bf16(ah, bl1, acc1, 0, 0, 0);
            acc0 = __builtin_amdgcn_mfma_f32_32x32x16_bf16(al, bh0, acc0, 0, 0, 0);
            acc1 = __builtin_amdgcn_mfma_f32_32x32x16_bf16(al, bh1, acc1, 0, 0, 0);
            acc0 = __builtin_amdgcn_mfma_f32_32x32x16_bf16(al, bl0, acc0, 0, 0, 0);
            acc1 = __builtin_amdgcn_mfma_f32_32x32x16_bf16(al, bl1, acc1, 0, 0, 0);
            apl += 16; bpl0 += 16; bpl1 += 16;
        }
        aph += 16; bph0 += 16; bph1 += 16;
    }

    float* pp = part + (size_t)blockIdx.z * (MB * FF);
    const int colA = n0 + l31, colB = colA + 32;
    const int rbase = m0 + 4 * (lane >> 5);
#pragma unroll
    for (int r = 0; r < 16; ++r) {
        const int row = rbase + (r & 3) + 8 * (r >> 2);
        pp[(size_t)row * FF + colA] = acc0[r];
        pp[(size_t)row * FF + colB] = acc1[r];
    }
}

// ---------------- split-K reduce + epilogue ----------------
// MODE 0: +bias -> hi/lo planes.  MODE 1: +bias -> hi/lo + f32.
// MODE 2: /(zn*mn) -> f32.        MODE 3: plain -> f32.
template <int MODE>
__global__ __launch_bounds__(256) void reduce_k(
    const float* __restrict__ part, const float* __restrict__ bias,
    const float* __restrict__ zn, const float* __restrict__ mn,
    unsigned short* __restrict__ hi, unsigned short* __restrict__ lo,
    float* __restrict__ fout)
{
    const size_t idx4 = (size_t)blockIdx.x * 256 + threadIdx.x;
    const size_t base = idx4 * 4;
    float s0 = 0.f, s1 = 0.f, s2 = 0.f, s3 = 0.f;
#pragma unroll
    for (int c = 0; c < 8; ++c) {
        const float4 p = *(const float4*)(part + (size_t)c * (MB * FF) + base);
        s0 += p.x; s1 += p.y; s2 += p.z; s3 += p.w;
    }
    const int col = (int)(base & 4095);
    const int row = (int)(base >> 12);
    if constexpr (MODE == 0 || MODE == 1) {
        s0 += bias[col]; s1 += bias[col + 1]; s2 += bias[col + 2]; s3 += bias[col + 3];
        unsigned short h0 = bf16_rne(s0), h1 = bf16_rne(s1), h2 = bf16_rne(s2), h3 = bf16_rne(s3);
        short4v hv = { (short)h0, (short)h1, (short)h2, (short)h3 };
        *(short4v*)(hi + base) = hv;
        short4v lv = { (short)bf16_rne(s0 - bf16_f(h0)), (short)bf16_rne(s1 - bf16_f(h1)),
                       (short)bf16_rne(s2 - bf16_f(h2)), (short)bf16_rne(s3 - bf16_f(h3)) };
        *(short4v*)(lo + base) = lv;
        if constexpr (MODE == 1) {
            float4 o = { s0, s1, s2, s3 };
            *(float4*)(fout + base) = o;
        }
    } else if constexpr (MODE == 2) {
        const float zr = zn[row];
        float4 o = { s0 / (zr * mn[col]), s1 / (zr * mn[col + 1]),
                     s2 / (zr * mn[col + 2]), s3 / (zr * mn[col + 3]) };
        *(float4*)(fout + base) = o;
    } else {
        float4 o = { s0, s1, s2, s3 };
        *(float4*)(fout + base) = o;
    }
}

// ---------------- softmax + shrinkage + renorm + entropy ----------------
__global__ __launch_bounds__(256) void softmax_shrink_kernel(
    const float* __restrict__ logits, unsigned short* __restrict__ w_hi,
    float* __restrict__ rowent)
{
    constexpr float THRESH = 1.0f / 4096.0f;
    constexpr float EPS = 1e-12f;
    __shared__ float srow[4096];
    __shared__ float red[256];
    const int row = blockIdx.x, tid = threadIdx.x;
    const float4* p = (const float4*)(logits + (size_t)row * FF);
    for (int i = tid; i < FF / 4; i += 256) ((float4*)srow)[i] = p[i];
    __syncthreads();

    float m = -INFINITY;
    for (int i = tid; i < FF; i += 256) m = fmaxf(m, srow[i]);
    m = block_reduce_max(m, red);

    float s = 0.f;
    for (int i = tid; i < FF; i += 256) {
        float e = expf(srow[i] - m);
        srow[i] = e; s += e;
    }
    s = block_reduce_sum(s, red);
    const float inv = 1.0f / s;

    float s2 = 0.f;
    for (int i = tid; i < FF; i += 256) {
        float w = srow[i] * inv;
        float d = w - THRESH;
        float w2 = fmaxf(d, 0.f) * w / (fabsf(d) + EPS);
        srow[i] = w2; s2 += w2;
    }
    __syncthreads();
    s2 = block_reduce_sum(s2, red);
    const float inv2 = 1.0f / fmaxf(s2, EPS);

    float ent = 0.f;
    for (int i = tid; i < FF; i += 256) {
        float w3 = srow[i] * inv2;
        w_hi[(size_t)row * FF + i] = bf16_rne(w3);
        ent -= w3 * logf(w3 + EPS);
    }
    ent = block_reduce_sum(ent, red);
    if (tid == 0) rowent[row] = ent;
}

__global__ __launch_bounds__(256) void loss_kernel(
    const float* __restrict__ rowent, float* __restrict__ out)
{
    __shared__ float red[256];
    const int tid = threadIdx.x;
    float tot = block_reduce_sum(rowent[tid], red);
    if (tid == 0) out[0] = (tot / 256.0f) * 0.0002f;
}

extern "C" void kernel_launch(void* const* d_in, const int* in_sizes, int n_in,
                              void* d_out, int out_size, void* d_ws, size_t ws_size,
                              hipStream_t stream)
{
    // inputs: x, memory, Wq, bq, Wk, bk, Wv, bv, Wo, bo
    const float* x   = (const float*)d_in[0];
    const float* mem = (const float*)d_in[1];
    const float* Wv  = (const float*)d_in[6];
    const float* bv  = (const float*)d_in[7];
    const float* Wo  = (const float*)d_in[8];
    const float* bo  = (const float*)d_in[9];
    float* out = (float*)d_out;

    char* ws = (char*)d_ws;
    unsigned short* T_hi  = (unsigned short*)(ws);                 // 32 MB  (transposed weight hi)
    unsigned short* T_lo  = (unsigned short*)(ws + 33554432ull);   // 32 MB
    unsigned short* M_hi  = (unsigned short*)(ws + 67108864ull);   // 32 MB  (mem split, native)
    unsigned short* M_lo  = (unsigned short*)(ws + 100663296ull);  // 32 MB
    float*          part  = (float*)(ws + 134217728ull);           // 32 MB  (8 split-K partials)
    unsigned short* x_hi  = (unsigned short*)(ws + 167772160ull);  // 2 MB
    unsigned short* x_lo  = (unsigned short*)(ws + 169869312ull);
    unsigned short* v_hi  = (unsigned short*)(ws + 171966464ull);
    unsigned short* v_lo  = (unsigned short*)(ws + 174063616ull);
    unsigned short* o_hi  = (unsigned short*)(ws + 176160768ull);
    unsigned short* o_lo  = (unsigned short*)(ws + 178257920ull);
    float*          o_f32 = (float*)(ws + 180355072ull);           // 4 MB
    float*          logit = (float*)(ws + 184549376ull);           // 4 MB
    unsigned short* w_hi  = (unsigned short*)(ws + 188743680ull);  // 2 MB
    float*          zn    = (float*)(ws + 190840832ull);
    float*          mn    = zn + MB;
    float*          rowe  = mn + FF;

    const dim3 blk(256);
    const dim3 gG(32, 4, 8);      // gemm: N/128, M/64, split-K 8
    const dim3 gT(128, 128);      // transpose tiles
    const int gR = (MB * FF) / (4 * 256);  // 1024 (reduce/split over 1M elems)

    // prep
    split_plain<<<gR, blk, 0, stream>>>(x, x_hi, x_lo);
    rownorm_kernel<<<FF, blk, 0, stream>>>(mem, mn, FF);
    split_plain<<<(FF * FF) / (4 * 256), blk, 0, stream>>>(mem, M_hi, M_lo);

    // v = z @ Wv + bv
    transpose_split<1><<<gT, blk, 0, stream>>>(Wv, T_hi, T_lo);
    gemm_sk<1><<<gG, blk, 0, stream>>>(x_hi, x_lo, T_hi, T_lo, part);
    reduce_k<0><<<gR, blk, 0, stream>>>(part, bv, nullptr, nullptr, v_hi, v_lo, nullptr);

    // o = v @ Wo + bo
    transpose_split<1><<<gT, blk, 0, stream>>>(Wo, T_hi, T_lo);
    gemm_sk<1><<<gG, blk, 0, stream>>>(v_hi, v_lo, T_hi, T_lo, part);
    reduce_k<1><<<gR, blk, 0, stream>>>(part, bo, nullptr, nullptr, o_hi, o_lo, o_f32);

    // logits = (o @ mem^T) / (zn x mn)   [mem native rows ARE B^T layout]
    rownorm_kernel<<<MB, blk, 0, stream>>>(o_f32, zn, FF);
    gemm_sk<1><<<gG, blk, 0, stream>>>(o_hi, o_lo, M_hi, M_lo, part);
    reduce_k<2><<<gR, blk, 0, stream>>>(part, nullptr, zn, mn, nullptr, nullptr, logit);

    // softmax/shrink/renorm/entropy -> w (bf16)
    softmax_shrink_kernel<<<MB, blk, 0, stream>>>(logit, w_hi, rowe);

    // z_hat = w @ mem  (plain bf16; needs mem^T planes)
    transpose_split<0><<<gT, blk, 0, stream>>>(mem, T_hi, nullptr);
    gemm_sk<0><<<gG, blk, 0, stream>>>(w_hi, nullptr, T_hi, nullptr, part);
    reduce_k<3><<<gR, blk, 0, stream>>>(part, nullptr, nullptr, nullptr, nullptr, nullptr, out);

    loss_kernel<<<1, blk, 0, stream>>>(rowe, out + (size_t)MB * FF);
}

// Round 3
// 429.496 us; speedup vs baseline: 1.9855x; 1.1297x over previous
//
#include <hip/hip_runtime.h>
#include <math.h>

// MultiHeadAttentionMemory: B=256, F=4096, M=4096 memories.
// seq_len==1 => attention==identity => o = (z@Wv+bv)@Wo+bo  (Wq/Wk dead).
// Split-bf16 (bf16x3: ah*bh + ah*bl + al*bh) MFMA for the 3 precision-
// sensitive GEMMs; plain bf16 MFMA for z_hat = w@mem.
#define MB 256
#define FF 4096

typedef __attribute__((ext_vector_type(8))) short short8v;
typedef __attribute__((ext_vector_type(4))) short short4v;
typedef __attribute__((ext_vector_type(16))) float f32x16;

__device__ __forceinline__ unsigned short bf16_rne(float f) {
    unsigned u = __builtin_bit_cast(unsigned, f);
    u += 0x7fffu + ((u >> 16) & 1u);
    return (unsigned short)(u >> 16);
}
__device__ __forceinline__ float bf16_f(unsigned short h) {
    unsigned u = ((unsigned)h) << 16;
    return __builtin_bit_cast(float, u);
}

// ---------------- reductions ----------------
__device__ __forceinline__ float block_reduce_sum(float v, float* red) {
    const int tid = threadIdx.x;
    red[tid] = v; __syncthreads();
    for (int s = 128; s > 0; s >>= 1) {
        if (tid < s) red[tid] += red[tid + s];
        __syncthreads();
    }
    float r = red[0]; __syncthreads();
    return r;
}
__device__ __forceinline__ float block_reduce_max(float v, float* red) {
    const int tid = threadIdx.x;
    red[tid] = v; __syncthreads();
    for (int s = 128; s > 0; s >>= 1) {
        if (tid < s) red[tid] = fmaxf(red[tid], red[tid + s]);
        __syncthreads();
    }
    float r = red[0]; __syncthreads();
    return r;
}

// dst[row] = max(||src[row,:]||, 1e-8)
__global__ __launch_bounds__(256) void rownorm_kernel(
    const float* __restrict__ src, float* __restrict__ dst, int ncols)
{
    __shared__ float red[256];
    const int row = blockIdx.x, tid = threadIdx.x;
    const float4* p = (const float4*)(src + (size_t)row * ncols);
    float s = 0.f;
    for (int i = tid; i < ncols / 4; i += 256) {
        float4 v = p[i];
        s += v.x * v.x + v.y * v.y + v.z * v.z + v.w * v.w;
    }
    float tot = block_reduce_sum(s, red);
    if (tid == 0) dst[row] = fmaxf(sqrtf(tot), 1e-8f);
}

// ---------------- fp32 -> bf16 hi/lo split (straight) ----------------
__global__ __launch_bounds__(256) void split_plain(
    const float* __restrict__ src, unsigned short* __restrict__ hi,
    unsigned short* __restrict__ lo)
{
    const size_t i4 = (size_t)blockIdx.x * 256 + threadIdx.x;
    const float4 v = *(const float4*)(src + i4 * 4);
    unsigned short h0 = bf16_rne(v.x), h1 = bf16_rne(v.y), h2 = bf16_rne(v.z), h3 = bf16_rne(v.w);
    short4v hv = { (short)h0, (short)h1, (short)h2, (short)h3 };
    *(short4v*)(hi + i4 * 4) = hv;
    short4v lv = { (short)bf16_rne(v.x - bf16_f(h0)), (short)bf16_rne(v.y - bf16_f(h1)),
                   (short)bf16_rne(v.z - bf16_f(h2)), (short)bf16_rne(v.w - bf16_f(h3)) };
    *(short4v*)(lo + i4 * 4) = lv;
}

// ---------------- mem: fused split + rownorm (one 64MB pass) ----------------
__global__ __launch_bounds__(256) void split_norm_mem(
    const float* __restrict__ src, unsigned short* __restrict__ hi,
    unsigned short* __restrict__ lo, float* __restrict__ nrm)
{
    __shared__ float red[256];
    const int row = blockIdx.x, tid = threadIdx.x;
    const float4* p = (const float4*)(src + (size_t)row * FF);
    float s = 0.f;
    for (int i = tid; i < FF / 4; i += 256) {
        float4 v = p[i];
        s += v.x * v.x + v.y * v.y + v.z * v.z + v.w * v.w;
        unsigned short h0 = bf16_rne(v.x), h1 = bf16_rne(v.y), h2 = bf16_rne(v.z), h3 = bf16_rne(v.w);
        const size_t ob = (size_t)row * FF + i * 4;
        short4v hv = { (short)h0, (short)h1, (short)h2, (short)h3 };
        *(short4v*)(hi + ob) = hv;
        short4v lv = { (short)bf16_rne(v.x - bf16_f(h0)), (short)bf16_rne(v.y - bf16_f(h1)),
                       (short)bf16_rne(v.z - bf16_f(h2)), (short)bf16_rne(v.w - bf16_f(h3)) };
        *(short4v*)(lo + ob) = lv;
    }
    float tot = block_reduce_sum(s, red);
    if (tid == 0) nrm[row] = fmaxf(sqrtf(tot), 1e-8f);
}

// ---------------- transpose + split: src[4096][4096] f32 -> dstT[n][k] bf16 ----------------
template <int WRITE_LO>
__global__ __launch_bounds__(256) void transpose_split(
    const float* __restrict__ src, unsigned short* __restrict__ hi,
    unsigned short* __restrict__ lo)
{
    __shared__ float tile[32][33];
    const int bj = blockIdx.x;  // col block of src (= out row block)
    const int bi = blockIdx.y;  // row block of src (= out col block)
    const int t = threadIdx.x;
    const int ty = t >> 3, tx4 = (t & 7) << 2;
    const float4 v = *(const float4*)(src + (size_t)(bi * 32 + ty) * FF + bj * 32 + tx4);
    tile[ty][tx4 + 0] = v.x; tile[ty][tx4 + 1] = v.y;
    tile[ty][tx4 + 2] = v.z; tile[ty][tx4 + 3] = v.w;
    __syncthreads();
    float o0 = tile[tx4 + 0][ty], o1 = tile[tx4 + 1][ty];
    float o2 = tile[tx4 + 2][ty], o3 = tile[tx4 + 3][ty];
    unsigned short h0 = bf16_rne(o0), h1 = bf16_rne(o1), h2 = bf16_rne(o2), h3 = bf16_rne(o3);
    const size_t ob = (size_t)(bj * 32 + ty) * FF + bi * 32 + tx4;
    short4v hv = { (short)h0, (short)h1, (short)h2, (short)h3 };
    *(short4v*)(hi + ob) = hv;
    if constexpr (WRITE_LO) {
        short4v lv = { (short)bf16_rne(o0 - bf16_f(h0)), (short)bf16_rne(o1 - bf16_f(h1)),
                       (short)bf16_rne(o2 - bf16_f(h2)), (short)bf16_rne(o3 - bf16_f(h3)) };
        *(short4v*)(lo + ob) = lv;
    }
}

// ---------------- MFMA GEMM, split-K, register double-buffered ----------------
// C[256][4096] = A[256][4096] @ BT[4096][4096]^T   (BT stored [n][k])
// grid (16, 4, 8); block 256 = 4 waves (2m x 2n); wave tile 32x128; K-chunk 512.
// SPLIT=1: bf16x3 (ah*bh + ah*bl + al*bh).
// NOTE: the pipeline prefetches one 16B fragment past the K-chunk end on the
// last step; all operand planes are laid out so that overread stays inside d_ws.
template <int SPLIT>
__global__ __launch_bounds__(256) void gemm_sk(
    const unsigned short* __restrict__ Ah, const unsigned short* __restrict__ Al,
    const unsigned short* __restrict__ Bh, const unsigned short* __restrict__ Bl,
    float* __restrict__ part)
{
    const int tid = threadIdx.x;
    const int lane = tid & 63, w = tid >> 6;
    const int wr = w >> 1, wc = w & 1;
    const int m0 = blockIdx.y * 64 + wr * 32;
    const int n0 = blockIdx.x * 256 + wc * 128;
    const int k0 = blockIdx.z * 512;
    const int l31 = lane & 31, lk = (lane >> 5) * 8;

    f32x16 acc0 = 0.0f, acc1 = 0.0f, acc2 = 0.0f, acc3 = 0.0f;

    const size_t arow = (size_t)(m0 + l31) * FF + k0 + lk;
    const unsigned short* aph = Ah + arow;
    const unsigned short* apl = SPLIT ? (Al + arow) : aph;
    const size_t brow = (size_t)(n0 + l31) * FF + k0 + lk;
    const unsigned short* bp0 = Bh + brow;
    const unsigned short* bp1 = bp0 + (size_t)32 * FF;
    const unsigned short* bp2 = bp0 + (size_t)64 * FF;
    const unsigned short* bp3 = bp0 + (size_t)96 * FF;
    const unsigned short* bq0 = SPLIT ? (Bl + brow) : bp0;
    const unsigned short* bq1 = bq0 + (size_t)32 * FF;
    const unsigned short* bq2 = bq0 + (size_t)64 * FF;
    const unsigned short* bq3 = bq0 + (size_t)96 * FF;

    short8v faA, falA, fbA0, fbA1, fbA2, fbA3, fblA0, fblA1, fblA2, fblA3;
    short8v faB, falB, fbB0, fbB1, fbB2, fbB3, fblB0, fblB1, fblB2, fblB3;

#define PREFETCH(S)                                                         \
    fa##S  = *(const short8v*)aph;  aph += 16;                              \
    fb##S##0 = *(const short8v*)bp0; bp0 += 16;                             \
    fb##S##1 = *(const short8v*)bp1; bp1 += 16;                             \
    fb##S##2 = *(const short8v*)bp2; bp2 += 16;                             \
    fb##S##3 = *(const short8v*)bp3; bp3 += 16;                             \
    if constexpr (SPLIT) {                                                  \
        fal##S  = *(const short8v*)apl;  apl += 16;                         \
        fbl##S##0 = *(const short8v*)bq0; bq0 += 16;                        \
        fbl##S##1 = *(const short8v*)bq1; bq1 += 16;                        \
        fbl##S##2 = *(const short8v*)bq2; bq2 += 16;                        \
        fbl##S##3 = *(const short8v*)bq3; bq3 += 16;                        \
    }

#define MM1(S, N)                                                              \
    acc##N = __builtin_amdgcn_mfma_f32_32x32x16_bf16(fa##S, fb##S##N, acc##N, 0, 0, 0); \
    if constexpr (SPLIT) {                                                     \
        acc##N = __builtin_amdgcn_mfma_f32_32x32x16_bf16(fa##S, fbl##S##N, acc##N, 0, 0, 0); \
        acc##N = __builtin_amdgcn_mfma_f32_32x32x16_bf16(fal##S, fb##S##N, acc##N, 0, 0, 0); \
    }

#define MMALL(S) MM1(S, 0) MM1(S, 1) MM1(S, 2) MM1(S, 3)

    PREFETCH(A)
    // 32 K-steps as 16 pipelined pairs; each prefetch is one step ahead.
    for (int ks = 0; ks < 16; ++ks) {
        PREFETCH(B)
        MMALL(A)
        PREFETCH(A)
        MMALL(B)
    }
#undef PREFETCH
#undef MM1
#undef MMALL

    float* pp = part + (size_t)blockIdx.z * (MB * FF);
    const int rbase = m0 + 4 * (lane >> 5);
#pragma unroll
    for (int r = 0; r < 16; ++r) {
        const int row = rbase + (r & 3) + 8 * (r >> 2);
        float* rowp = pp + (size_t)row * FF + n0 + l31;
        rowp[0]  = acc0[r];
        rowp[32] = acc1[r];
        rowp[64] = acc2[r];
        rowp[96] = acc3[r];
    }
}

// ---------------- split-K reduce + epilogue ----------------
// MODE 0: +bias -> hi/lo planes.  MODE 1: +bias -> hi/lo + f32.
// MODE 2: /(zn*mn) -> f32.        MODE 3: plain -> f32.
template <int MODE>
__global__ __launch_bounds__(256) void reduce_k(
    const float* __restrict__ part, const float* __restrict__ bias,
    const float* __restrict__ zn, const float* __restrict__ mn,
    unsigned short* __restrict__ hi, unsigned short* __restrict__ lo,
    float* __restrict__ fout)
{
    const size_t idx4 = (size_t)blockIdx.x * 256 + threadIdx.x;
    const size_t base = idx4 * 4;
    float s0 = 0.f, s1 = 0.f, s2 = 0.f, s3 = 0.f;
#pragma unroll
    for (int c = 0; c < 8; ++c) {
        const float4 p = *(const float4*)(part + (size_t)c * (MB * FF) + base);
        s0 += p.x; s1 += p.y; s2 += p.z; s3 += p.w;
    }
    const int col = (int)(base & 4095);
    const int row = (int)(base >> 12);
    if constexpr (MODE == 0 || MODE == 1) {
        s0 += bias[col]; s1 += bias[col + 1]; s2 += bias[col + 2]; s3 += bias[col + 3];
        unsigned short h0 = bf16_rne(s0), h1 = bf16_rne(s1), h2 = bf16_rne(s2), h3 = bf16_rne(s3);
        short4v hv = { (short)h0, (short)h1, (short)h2, (short)h3 };
        *(short4v*)(hi + base) = hv;
        short4v lv = { (short)bf16_rne(s0 - bf16_f(h0)), (short)bf16_rne(s1 - bf16_f(h1)),
                       (short)bf16_rne(s2 - bf16_f(h2)), (short)bf16_rne(s3 - bf16_f(h3)) };
        *(short4v*)(lo + base) = lv;
        if constexpr (MODE == 1) {
            float4 o = { s0, s1, s2, s3 };
            *(float4*)(fout + base) = o;
        }
    } else if constexpr (MODE == 2) {
        const float zr = zn[row];
        float4 o = { s0 / (zr * mn[col]), s1 / (zr * mn[col + 1]),
                     s2 / (zr * mn[col + 2]), s3 / (zr * mn[col + 3]) };
        *(float4*)(fout + base) = o;
    } else {
        float4 o = { s0, s1, s2, s3 };
        *(float4*)(fout + base) = o;
    }
}

// ---------------- softmax + shrinkage + renorm + entropy ----------------
__global__ __launch_bounds__(256) void softmax_shrink_kernel(
    const float* __restrict__ logits, unsigned short* __restrict__ w_hi,
    float* __restrict__ rowent)
{
    constexpr float THRESH = 1.0f / 4096.0f;
    constexpr float EPS = 1e-12f;
    __shared__ float srow[4096];
    __shared__ float red[256];
    const int row = blockIdx.x, tid = threadIdx.x;
    const float4* p = (const float4*)(logits + (size_t)row * FF);
    for (int i = tid; i < FF / 4; i += 256) ((float4*)srow)[i] = p[i];
    __syncthreads();

    float m = -INFINITY;
    for (int i = tid; i < FF; i += 256) m = fmaxf(m, srow[i]);
    m = block_reduce_max(m, red);

    float s = 0.f;
    for (int i = tid; i < FF; i += 256) {
        float e = expf(srow[i] - m);
        srow[i] = e; s += e;
    }
    s = block_reduce_sum(s, red);
    const float inv = 1.0f / s;

    float s2 = 0.f;
    for (int i = tid; i < FF; i += 256) {
        float w = srow[i] * inv;
        float d = w - THRESH;
        float w2 = fmaxf(d, 0.f) * w / (fabsf(d) + EPS);
        srow[i] = w2; s2 += w2;
    }
    __syncthreads();
    s2 = block_reduce_sum(s2, red);
    const float inv2 = 1.0f / fmaxf(s2, EPS);

    float ent = 0.f;
    for (int i = tid; i < FF; i += 256) {
        float w3 = srow[i] * inv2;
        w_hi[(size_t)row * FF + i] = bf16_rne(w3);
        ent -= w3 * logf(w3 + EPS);
    }
    ent = block_reduce_sum(ent, red);
    if (tid == 0) rowent[row] = ent;
}

__global__ __launch_bounds__(256) void loss_kernel(
    const float* __restrict__ rowent, float* __restrict__ out)
{
    __shared__ float red[256];
    const int tid = threadIdx.x;
    float tot = block_reduce_sum(rowent[tid], red);
    if (tid == 0) out[0] = (tot / 256.0f) * 0.0002f;
}

extern "C" void kernel_launch(void* const* d_in, const int* in_sizes, int n_in,
                              void* d_out, int out_size, void* d_ws, size_t ws_size,
                              hipStream_t stream)
{
    // inputs: x, memory, Wq, bq, Wk, bk, Wv, bv, Wo, bo
    const float* x   = (const float*)d_in[0];
    const float* mem = (const float*)d_in[1];
    const float* Wv  = (const float*)d_in[6];
    const float* bv  = (const float*)d_in[7];
    const float* Wo  = (const float*)d_in[8];
    const float* bo  = (const float*)d_in[9];
    float* out = (float*)d_out;

    char* ws = (char*)d_ws;
    unsigned short* T_hi  = (unsigned short*)(ws);                 // 32 MB  (transposed weight hi)
    unsigned short* T_lo  = (unsigned short*)(ws + 33554432ull);   // 32 MB
    unsigned short* M_hi  = (unsigned short*)(ws + 67108864ull);   // 32 MB  (mem split, native)
    unsigned short* M_lo  = (unsigned short*)(ws + 100663296ull);  // 32 MB
    float*          part  = (float*)(ws + 134217728ull);           // 32 MB  (8 split-K partials)
    unsigned short* x_hi  = (unsigned short*)(ws + 167772160ull);  // 2 MB
    unsigned short* x_lo  = (unsigned short*)(ws + 169869312ull);
    unsigned short* v_hi  = (unsigned short*)(ws + 171966464ull);
    unsigned short* v_lo  = (unsigned short*)(ws + 174063616ull);
    unsigned short* o_hi  = (unsigned short*)(ws + 176160768ull);
    unsigned short* o_lo  = (unsigned short*)(ws + 178257920ull);
    float*          o_f32 = (float*)(ws + 180355072ull);           // 4 MB
    float*          logit = (float*)(ws + 184549376ull);           // 4 MB
    unsigned short* w_hi  = (unsigned short*)(ws + 188743680ull);  // 2 MB
    float*          zn    = (float*)(ws + 190840832ull);
    float*          mn    = zn + MB;
    float*          rowe  = mn + FF;

    const dim3 blk(256);
    const dim3 gG(16, 4, 8);      // gemm: N/256, M/64, split-K 8
    const dim3 gT(128, 128);      // transpose tiles
    const int gR = (MB * FF) / (4 * 256);  // 1024

    // prep
    split_plain<<<gR, blk, 0, stream>>>(x, x_hi, x_lo);
    split_norm_mem<<<FF, blk, 0, stream>>>(mem, M_hi, M_lo, mn);

    // v = z @ Wv + bv
    transpose_split<1><<<gT, blk, 0, stream>>>(Wv, T_hi, T_lo);
    gemm_sk<1><<<gG, blk, 0, stream>>>(x_hi, x_lo, T_hi, T_lo, part);
    reduce_k<0><<<gR, blk, 0, stream>>>(part, bv, nullptr, nullptr, v_hi, v_lo, nullptr);

    // o = v @ Wo + bo
    transpose_split<1><<<gT, blk, 0, stream>>>(Wo, T_hi, T_lo);
    gemm_sk<1><<<gG, blk, 0, stream>>>(v_hi, v_lo, T_hi, T_lo, part);
    reduce_k<1><<<gR, blk, 0, stream>>>(part, bo, nullptr, nullptr, o_hi, o_lo, o_f32);

    // logits = (o @ mem^T) / (zn x mn)   [mem native rows ARE B^T layout]
    rownorm_kernel<<<MB, blk, 0, stream>>>(o_f32, zn, FF);
    gemm_sk<1><<<gG, blk, 0, stream>>>(o_hi, o_lo, M_hi, M_lo, part);
    reduce_k<2><<<gR, blk, 0, stream>>>(part, nullptr, zn, mn, nullptr, nullptr, logit);

    // softmax/shrink/renorm/entropy -> w (bf16)
    softmax_shrink_kernel<<<MB, blk, 0, stream>>>(logit, w_hi, rowe);

    // z_hat = w @ mem  (plain bf16; needs mem^T planes)
    transpose_split<0><<<gT, blk, 0, stream>>>(mem, T_hi, nullptr);
    gemm_sk<0><<<gG, blk, 0, stream>>>(w_hi, nullptr, T_hi, nullptr, part);
    reduce_k<3><<<gR, blk, 0, stream>>>(part, nullptr, nullptr, nullptr, nullptr, nullptr, out);

    loss_kernel<<<1, blk, 0, stream>>>(rowe, out + (size_t)MB * FF);
}

// Round 4
// 344.452 us; speedup vs baseline: 2.4757x; 1.2469x over previous
//
#include <hip/hip_runtime.h>
#include <math.h>

// MultiHeadAttentionMemory: B=256, F=4096, M=4096 memories.
// seq_len==1 => attention==identity => o = (z@Wv+bv)@Wo+bo  (Wq/Wk dead).
// Split-bf16 (bf16x3: ah*bh + ah*bl + al*bh) MFMA for the 3 precision-
// sensitive GEMMs; plain bf16 MFMA for z_hat = w@mem.
// GEMM structure: B planes via global_load_lds double-buffered LDS ([k8][n]
// 16B-block layout, conflict-free ds_read_b128); A planes register-direct
// with 1-tile-ahead prefetch; 2-phase barrier loop (m97 pattern).
#define MB 256
#define FF 4096

typedef __attribute__((ext_vector_type(8))) short short8v;
typedef __attribute__((ext_vector_type(4))) short short4v;
typedef __attribute__((ext_vector_type(16))) float f32x16;

__device__ __forceinline__ unsigned short bf16_rne(float f) {
    unsigned u = __builtin_bit_cast(unsigned, f);
    u += 0x7fffu + ((u >> 16) & 1u);
    return (unsigned short)(u >> 16);
}
__device__ __forceinline__ float bf16_f(unsigned short h) {
    unsigned u = ((unsigned)h) << 16;
    return __builtin_bit_cast(float, u);
}

// async global->LDS, 16B per lane; lds ptr must be wave-uniform.
#define GLL16(g, l)                                                          \
    __builtin_amdgcn_global_load_lds(                                        \
        (const __attribute__((address_space(1))) unsigned int*)(g),          \
        (__attribute__((address_space(3))) unsigned int*)(l), 16, 0, 0)

// ---------------- reductions ----------------
__device__ __forceinline__ float block_reduce_sum(float v, float* red) {
    const int tid = threadIdx.x;
    red[tid] = v; __syncthreads();
    for (int s = 128; s > 0; s >>= 1) {
        if (tid < s) red[tid] += red[tid + s];
        __syncthreads();
    }
    float r = red[0]; __syncthreads();
    return r;
}
__device__ __forceinline__ float block_reduce_max(float v, float* red) {
    const int tid = threadIdx.x;
    red[tid] = v; __syncthreads();
    for (int s = 128; s > 0; s >>= 1) {
        if (tid < s) red[tid] = fmaxf(red[tid], red[tid + s]);
        __syncthreads();
    }
    float r = red[0]; __syncthreads();
    return r;
}

// dst[row] = max(||src[row,:]||, 1e-8)
__global__ __launch_bounds__(256) void rownorm_kernel(
    const float* __restrict__ src, float* __restrict__ dst, int ncols)
{
    __shared__ float red[256];
    const int row = blockIdx.x, tid = threadIdx.x;
    const float4* p = (const float4*)(src + (size_t)row * ncols);
    float s = 0.f;
    for (int i = tid; i < ncols / 4; i += 256) {
        float4 v = p[i];
        s += v.x * v.x + v.y * v.y + v.z * v.z + v.w * v.w;
    }
    float tot = block_reduce_sum(s, red);
    if (tid == 0) dst[row] = fmaxf(sqrtf(tot), 1e-8f);
}

// ---------------- fp32 -> bf16 hi/lo split (straight) ----------------
__global__ __launch_bounds__(256) void split_plain(
    const float* __restrict__ src, unsigned short* __restrict__ hi,
    unsigned short* __restrict__ lo)
{
    const size_t i4 = (size_t)blockIdx.x * 256 + threadIdx.x;
    const float4 v = *(const float4*)(src + i4 * 4);
    unsigned short h0 = bf16_rne(v.x), h1 = bf16_rne(v.y), h2 = bf16_rne(v.z), h3 = bf16_rne(v.w);
    short4v hv = { (short)h0, (short)h1, (short)h2, (short)h3 };
    *(short4v*)(hi + i4 * 4) = hv;
    short4v lv = { (short)bf16_rne(v.x - bf16_f(h0)), (short)bf16_rne(v.y - bf16_f(h1)),
                   (short)bf16_rne(v.z - bf16_f(h2)), (short)bf16_rne(v.w - bf16_f(h3)) };
    *(short4v*)(lo + i4 * 4) = lv;
}

// ---------------- mem: fused split + rownorm (one 64MB pass) ----------------
__global__ __launch_bounds__(256) void split_norm_mem(
    const float* __restrict__ src, unsigned short* __restrict__ hi,
    unsigned short* __restrict__ lo, float* __restrict__ nrm)
{
    __shared__ float red[256];
    const int row = blockIdx.x, tid = threadIdx.x;
    const float4* p = (const float4*)(src + (size_t)row * FF);
    float s = 0.f;
    for (int i = tid; i < FF / 4; i += 256) {
        float4 v = p[i];
        s += v.x * v.x + v.y * v.y + v.z * v.z + v.w * v.w;
        unsigned short h0 = bf16_rne(v.x), h1 = bf16_rne(v.y), h2 = bf16_rne(v.z), h3 = bf16_rne(v.w);
        const size_t ob = (size_t)row * FF + i * 4;
        short4v hv = { (short)h0, (short)h1, (short)h2, (short)h3 };
        *(short4v*)(hi + ob) = hv;
        short4v lv = { (short)bf16_rne(v.x - bf16_f(h0)), (short)bf16_rne(v.y - bf16_f(h1)),
                       (short)bf16_rne(v.z - bf16_f(h2)), (short)bf16_rne(v.w - bf16_f(h3)) };
        *(short4v*)(lo + ob) = lv;
    }
    float tot = block_reduce_sum(s, red);
    if (tid == 0) nrm[row] = fmaxf(sqrtf(tot), 1e-8f);
}

// ---------------- transpose + split: src[4096][4096] f32 -> dstT[n][k] bf16 ----------------
template <int WRITE_LO>
__global__ __launch_bounds__(256) void transpose_split(
    const float* __restrict__ src, unsigned short* __restrict__ hi,
    unsigned short* __restrict__ lo)
{
    __shared__ float tile[32][33];
    const int bj = blockIdx.x;  // col block of src (= out row block)
    const int bi = blockIdx.y;  // row block of src (= out col block)
    const int t = threadIdx.x;
    const int ty = t >> 3, tx4 = (t & 7) << 2;
    const float4 v = *(const float4*)(src + (size_t)(bi * 32 + ty) * FF + bj * 32 + tx4);
    tile[ty][tx4 + 0] = v.x; tile[ty][tx4 + 1] = v.y;
    tile[ty][tx4 + 2] = v.z; tile[ty][tx4 + 3] = v.w;
    __syncthreads();
    float o0 = tile[tx4 + 0][ty], o1 = tile[tx4 + 1][ty];
    float o2 = tile[tx4 + 2][ty], o3 = tile[tx4 + 3][ty];
    unsigned short h0 = bf16_rne(o0), h1 = bf16_rne(o1), h2 = bf16_rne(o2), h3 = bf16_rne(o3);
    const size_t ob = (size_t)(bj * 32 + ty) * FF + bi * 32 + tx4;
    short4v hv = { (short)h0, (short)h1, (short)h2, (short)h3 };
    *(short4v*)(hi + ob) = hv;
    if constexpr (WRITE_LO) {
        short4v lv = { (short)bf16_rne(o0 - bf16_f(h0)), (short)bf16_rne(o1 - bf16_f(h1)),
                       (short)bf16_rne(o2 - bf16_f(h2)), (short)bf16_rne(o3 - bf16_f(h3)) };
        *(short4v*)(lo + ob) = lv;
    }
}

// ---------------- MFMA GEMM, split-K, LDS-staged B ----------------
// C[256][4096] = A[256][4096] @ BT^T  (BT stored [n][k] bf16 planes).
// grid (32, 2, 8); block 256 = 4 waves (2m x 2n), block tile 128x128,
// wave tile 64x64 (2x2 subtiles of 32), BK=32, K-chunk 512 (16 tiles).
// B hi/lo staged via global_load_lds into LDS [buf][plane][k8][n] 16B-blocks;
// A hi/lo register-direct with 1-tile-ahead prefetch.
template <int SPLIT>
__global__ __launch_bounds__(256, 2) void gemm_sk(
    const unsigned short* __restrict__ Ah, const unsigned short* __restrict__ Al,
    const unsigned short* __restrict__ Bh, const unsigned short* __restrict__ Bl,
    float* __restrict__ part)
{
    __shared__ unsigned short Bs[2][2][4096];  // [buf][plane][8KB of shorts]

    const int tid = threadIdx.x;
    const int lane = tid & 63, w = tid >> 6;
    const int wr = w >> 1, wc = w & 1;
    const int m0 = blockIdx.y * 128 + wr * 64;
    const int bn0 = blockIdx.x * 128;
    const int k0 = blockIdx.z * 512;
    const int l31 = lane & 31;

    // ---- staging addresses (B): slot s = i*256+tid -> k8=i*2+(tid>>7), n=tid&127
    const size_t brow_off = (size_t)(bn0 + (tid & 127)) * FF + k0 + (tid >> 7) * 8;
    const unsigned short* bsh = Bh + brow_off;
    const unsigned short* bsl = SPLIT ? (Bl + brow_off) : bsh;
    char* const lwave = (char*)Bs + (tid >> 6) * 1024;  // wave-uniform

#define STAGE(BUF, T_)                                                        \
    {                                                                         \
        GLL16(bsh + (T_) * 32,      lwave + (BUF) * 16384 + 0);               \
        GLL16(bsh + (T_) * 32 + 16, lwave + (BUF) * 16384 + 4096);            \
        if constexpr (SPLIT) {                                                \
            GLL16(bsl + (T_) * 32,      lwave + (BUF) * 16384 + 8192);        \
            GLL16(bsl + (T_) * 32 + 16, lwave + (BUF) * 16384 + 12288);       \
        }                                                                     \
    }

    // ---- B fragment reads: byte = (k8*128+n)*16, k8=ks*2+(lane>>5),
    //      n = wc*64 + nsub*32 + l31  -> two contiguous 512B runs per wave.
    const char* const fragbase =
        (const char*)Bs + (((lane >> 5) * 128) + wc * 64 + l31) * 16;
#define BFRAG(BUF, P, KS, NS)                                                 \
    (*(const short8v*)(fragbase + (BUF) * 16384 + (P) * 8192 + (KS) * 4096 + (NS) * 512))

    // ---- A pointers (register-direct)
    const size_t arow = (size_t)(m0 + l31) * FF + k0 + (lane >> 5) * 8;
    const unsigned short* a0h = Ah + arow;
    const unsigned short* a1h = a0h + (size_t)32 * FF;
    const unsigned short* a0l = SPLIT ? (Al + arow) : a0h;
    const unsigned short* a1l = a0l + (size_t)32 * FF;

    short8v cA_0h0, cA_0h1, cA_1h0, cA_1h1, cA_0l0, cA_0l1, cA_1l0, cA_1l1;
    short8v nA_0h0, nA_0h1, nA_1h0, nA_1h1, nA_0l0, nA_0l1, nA_1l0, nA_1l1;

#define LOADA(SET, T_)                                                        \
    {                                                                         \
        const int o_ = (T_) * 32;                                             \
        SET##_0h0 = *(const short8v*)(a0h + o_);                              \
        SET##_0h1 = *(const short8v*)(a0h + o_ + 16);                         \
        SET##_1h0 = *(const short8v*)(a1h + o_);                              \
        SET##_1h1 = *(const short8v*)(a1h + o_ + 16);                         \
        if constexpr (SPLIT) {                                                \
            SET##_0l0 = *(const short8v*)(a0l + o_);                          \
            SET##_0l1 = *(const short8v*)(a0l + o_ + 16);                     \
            SET##_1l0 = *(const short8v*)(a1l + o_);                          \
            SET##_1l1 = *(const short8v*)(a1l + o_ + 16);                     \
        }                                                                     \
    }

    f32x16 acc00 = 0.0f, acc01 = 0.0f, acc10 = 0.0f, acc11 = 0.0f;

#define MFMA(A_, B_, C_) C_ = __builtin_amdgcn_mfma_f32_32x32x16_bf16(A_, B_, C_, 0, 0, 0)
#define MMKS(SET, BUF, KS)                                                    \
    {                                                                         \
        short8v bh0 = BFRAG(BUF, 0, KS, 0);                                   \
        short8v bh1 = BFRAG(BUF, 0, KS, 1);                                   \
        MFMA(SET##_0h##KS, bh0, acc00); MFMA(SET##_0h##KS, bh1, acc01);       \
        MFMA(SET##_1h##KS, bh0, acc10); MFMA(SET##_1h##KS, bh1, acc11);       \
        if constexpr (SPLIT) {                                                \
            short8v bl0 = BFRAG(BUF, 1, KS, 0);                               \
            short8v bl1 = BFRAG(BUF, 1, KS, 1);                               \
            MFMA(SET##_0h##KS, bl0, acc00); MFMA(SET##_0h##KS, bl1, acc01);   \
            MFMA(SET##_1h##KS, bl0, acc10); MFMA(SET##_1h##KS, bl1, acc11);   \
            MFMA(SET##_0l##KS, bh0, acc00); MFMA(SET##_0l##KS, bh1, acc01);   \
            MFMA(SET##_1l##KS, bh0, acc10); MFMA(SET##_1l##KS, bh1, acc11);   \
        }                                                                     \
    }

    // prologue: tile 0 -> buf0, A(0) -> cA
    STAGE(0, 0)
    LOADA(cA, 0)
    __syncthreads();

#pragma unroll
    for (int tp = 0; tp < 8; ++tp) {
        const int t = tp * 2;
        // even tile t (buf0, cA); prefetch t+1
        STAGE(1, t + 1)
        LOADA(nA, t + 1)
        MMKS(cA, 0, 0)
        MMKS(cA, 0, 1)
        __syncthreads();
        // odd tile t+1 (buf1, nA); prefetch t+2
        if (tp < 7) { STAGE(0, t + 2) }
        LOADA(cA, (t + 2) & 15)
        MMKS(nA, 1, 0)
        MMKS(nA, 1, 1)
        __syncthreads();
    }
#undef STAGE
#undef BFRAG
#undef LOADA
#undef MFMA
#undef MMKS

    float* pp = part + (size_t)blockIdx.z * (MB * FF);
    const int rbase = m0 + 4 * (lane >> 5);
    const int c0 = bn0 + wc * 64 + l31;
#pragma unroll
    for (int r = 0; r < 16; ++r) {
        const int row0 = rbase + (r & 3) + 8 * (r >> 2);
        float* rp0 = pp + (size_t)row0 * FF + c0;
        rp0[0]  = acc00[r];
        rp0[32] = acc01[r];
        float* rp1 = rp0 + (size_t)32 * FF;
        rp1[0]  = acc10[r];
        rp1[32] = acc11[r];
    }
}

// ---------------- split-K reduce + epilogue ----------------
// MODE 0: +bias -> hi/lo planes.  MODE 1: +bias -> hi/lo + f32.
// MODE 2: /(zn*mn) -> f32.        MODE 3: plain -> f32.
template <int MODE>
__global__ __launch_bounds__(256) void reduce_k(
    const float* __restrict__ part, const float* __restrict__ bias,
    const float* __restrict__ zn, const float* __restrict__ mn,
    unsigned short* __restrict__ hi, unsigned short* __restrict__ lo,
    float* __restrict__ fout)
{
    const size_t idx4 = (size_t)blockIdx.x * 256 + threadIdx.x;
    const size_t base = idx4 * 4;
    float s0 = 0.f, s1 = 0.f, s2 = 0.f, s3 = 0.f;
#pragma unroll
    for (int c = 0; c < 8; ++c) {
        const float4 p = *(const float4*)(part + (size_t)c * (MB * FF) + base);
        s0 += p.x; s1 += p.y; s2 += p.z; s3 += p.w;
    }
    const int col = (int)(base & 4095);
    const int row = (int)(base >> 12);
    if constexpr (MODE == 0 || MODE == 1) {
        s0 += bias[col]; s1 += bias[col + 1]; s2 += bias[col + 2]; s3 += bias[col + 3];
        unsigned short h0 = bf16_rne(s0), h1 = bf16_rne(s1), h2 = bf16_rne(s2), h3 = bf16_rne(s3);
        short4v hv = { (short)h0, (short)h1, (short)h2, (short)h3 };
        *(short4v*)(hi + base) = hv;
        short4v lv = { (short)bf16_rne(s0 - bf16_f(h0)), (short)bf16_rne(s1 - bf16_f(h1)),
                       (short)bf16_rne(s2 - bf16_f(h2)), (short)bf16_rne(s3 - bf16_f(h3)) };
        *(short4v*)(lo + base) = lv;
        if constexpr (MODE == 1) {
            float4 o = { s0, s1, s2, s3 };
            *(float4*)(fout + base) = o;
        }
    } else if constexpr (MODE == 2) {
        const float zr = zn[row];
        float4 o = { s0 / (zr * mn[col]), s1 / (zr * mn[col + 1]),
                     s2 / (zr * mn[col + 2]), s3 / (zr * mn[col + 3]) };
        *(float4*)(fout + base) = o;
    } else {
        float4 o = { s0, s1, s2, s3 };
        *(float4*)(fout + base) = o;
    }
}

// ---------------- softmax + shrinkage + renorm + entropy ----------------
__global__ __launch_bounds__(256) void softmax_shrink_kernel(
    const float* __restrict__ logits, unsigned short* __restrict__ w_hi,
    float* __restrict__ rowent)
{
    constexpr float THRESH = 1.0f / 4096.0f;
    constexpr float EPS = 1e-12f;
    __shared__ float srow[4096];
    __shared__ float red[256];
    const int row = blockIdx.x, tid = threadIdx.x;
    const float4* p = (const float4*)(logits + (size_t)row * FF);
    for (int i = tid; i < FF / 4; i += 256) ((float4*)srow)[i] = p[i];
    __syncthreads();

    float m = -INFINITY;
    for (int i = tid; i < FF; i += 256) m = fmaxf(m, srow[i]);
    m = block_reduce_max(m, red);

    float s = 0.f;
    for (int i = tid; i < FF; i += 256) {
        float e = expf(srow[i] - m);
        srow[i] = e; s += e;
    }
    s = block_reduce_sum(s, red);
    const float inv = 1.0f / s;

    float s2 = 0.f;
    for (int i = tid; i < FF; i += 256) {
        float w = srow[i] * inv;
        float d = w - THRESH;
        float w2 = fmaxf(d, 0.f) * w / (fabsf(d) + EPS);
        srow[i] = w2; s2 += w2;
    }
    __syncthreads();
    s2 = block_reduce_sum(s2, red);
    const float inv2 = 1.0f / fmaxf(s2, EPS);

    float ent = 0.f;
    for (int i = tid; i < FF; i += 256) {
        float w3 = srow[i] * inv2;
        w_hi[(size_t)row * FF + i] = bf16_rne(w3);
        ent -= w3 * logf(w3 + EPS);
    }
    ent = block_reduce_sum(ent, red);
    if (tid == 0) rowent[row] = ent;
}

__global__ __launch_bounds__(256) void loss_kernel(
    const float* __restrict__ rowent, float* __restrict__ out)
{
    __shared__ float red[256];
    const int tid = threadIdx.x;
    float tot = block_reduce_sum(rowent[tid], red);
    if (tid == 0) out[0] = (tot / 256.0f) * 0.0002f;
}

extern "C" void kernel_launch(void* const* d_in, const int* in_sizes, int n_in,
                              void* d_out, int out_size, void* d_ws, size_t ws_size,
                              hipStream_t stream)
{
    // inputs: x, memory, Wq, bq, Wk, bk, Wv, bv, Wo, bo
    const float* x   = (const float*)d_in[0];
    const float* mem = (const float*)d_in[1];
    const float* Wv  = (const float*)d_in[6];
    const float* bv  = (const float*)d_in[7];
    const float* Wo  = (const float*)d_in[8];
    const float* bo  = (const float*)d_in[9];
    float* out = (float*)d_out;

    char* ws = (char*)d_ws;
    unsigned short* T_hi  = (unsigned short*)(ws);                 // 32 MB  (transposed weight hi)
    unsigned short* T_lo  = (unsigned short*)(ws + 33554432ull);   // 32 MB
    unsigned short* M_hi  = (unsigned short*)(ws + 67108864ull);   // 32 MB  (mem split, native)
    unsigned short* M_lo  = (unsigned short*)(ws + 100663296ull);  // 32 MB
    float*          part  = (float*)(ws + 134217728ull);           // 32 MB  (8 split-K partials)
    unsigned short* x_hi  = (unsigned short*)(ws + 167772160ull);  // 2 MB
    unsigned short* x_lo  = (unsigned short*)(ws + 169869312ull);
    unsigned short* v_hi  = (unsigned short*)(ws + 171966464ull);
    unsigned short* v_lo  = (unsigned short*)(ws + 174063616ull);
    unsigned short* o_hi  = (unsigned short*)(ws + 176160768ull);
    unsigned short* o_lo  = (unsigned short*)(ws + 178257920ull);
    float*          o_f32 = (float*)(ws + 180355072ull);           // 4 MB
    float*          logit = (float*)(ws + 184549376ull);           // 4 MB
    unsigned short* w_hi  = (unsigned short*)(ws + 188743680ull);  // 2 MB
    float*          zn    = (float*)(ws + 190840832ull);
    float*          mn    = zn + MB;
    float*          rowe  = mn + FF;

    const dim3 blk(256);
    const dim3 gG(32, 2, 8);      // gemm: N/128, M/128, split-K 8
    const dim3 gT(128, 128);      // transpose tiles
    const int gR = (MB * FF) / (4 * 256);  // 1024

    // prep
    split_plain<<<gR, blk, 0, stream>>>(x, x_hi, x_lo);
    split_norm_mem<<<FF, blk, 0, stream>>>(mem, M_hi, M_lo, mn);

    // v = z @ Wv + bv
    transpose_split<1><<<gT, blk, 0, stream>>>(Wv, T_hi, T_lo);
    gemm_sk<1><<<gG, blk, 0, stream>>>(x_hi, x_lo, T_hi, T_lo, part);
    reduce_k<0><<<gR, blk, 0, stream>>>(part, bv, nullptr, nullptr, v_hi, v_lo, nullptr);

    // o = v @ Wo + bo
    transpose_split<1><<<gT, blk, 0, stream>>>(Wo, T_hi, T_lo);
    gemm_sk<1><<<gG, blk, 0, stream>>>(v_hi, v_lo, T_hi, T_lo, part);
    reduce_k<1><<<gR, blk, 0, stream>>>(part, bo, nullptr, nullptr, o_hi, o_lo, o_f32);

    // logits = (o @ mem^T) / (zn x mn)   [mem native rows ARE B^T layout]
    rownorm_kernel<<<MB, blk, 0, stream>>>(o_f32, zn, FF);
    gemm_sk<1><<<gG, blk, 0, stream>>>(o_hi, o_lo, M_hi, M_lo, part);
    reduce_k<2><<<gR, blk, 0, stream>>>(part, nullptr, zn, mn, nullptr, nullptr, logit);

    // softmax/shrink/renorm/entropy -> w (bf16)
    softmax_shrink_kernel<<<MB, blk, 0, stream>>>(logit, w_hi, rowe);

    // z_hat = w @ mem  (plain bf16; needs mem^T planes)
    transpose_split<0><<<gT, blk, 0, stream>>>(mem, T_hi, nullptr);
    gemm_sk<0><<<gG, blk, 0, stream>>>(w_hi, nullptr, T_hi, nullptr, part);
    reduce_k<3><<<gR, blk, 0, stream>>>(part, nullptr, nullptr, nullptr, nullptr, nullptr, out);

    loss_kernel<<<1, blk, 0, stream>>>(rowe, out + (size_t)MB * FF);
}